// Round 2
// baseline (108.972 us; speedup 1.0000x reference)
//
#include <hip/hip_runtime.h>
#include <math.h>

#define NPOS 1024   // H*W
#define DH   32     // dim head
#define NBH  8      // B * HEADS
#define CH   256
#define INNER 128   // HEADS*DIM_HEAD

// ---------------------------------------------------------------------------
// Kernel A: fused QKV projection.  out_p[b,i,n] = sum_c W_p[i,c] * x[b,c,n]
// One x load feeds 12 accumulators (4 i x {Q,K,V}).
// ---------------------------------------------------------------------------
__global__ __launch_bounds__(256) void proj_kernel(
    const float* __restrict__ x, const float* __restrict__ Wq,
    const float* __restrict__ Wk, const float* __restrict__ Wv,
    float* __restrict__ Q, float* __restrict__ K, float* __restrict__ V)
{
  const int lane = threadIdx.x & 63;
  const int it   = threadIdx.x >> 6;        // 0..3
  const int n    = blockIdx.x * 64 + lane;  // 0..1023
  const int i0   = blockIdx.y * 16 + it * 4;
  const int b    = blockIdx.z;

  const float* xb = x  + (size_t)b * CH * NPOS + n;
  const float* wq = Wq + (size_t)i0 * CH;
  const float* wk = Wk + (size_t)i0 * CH;
  const float* wv = Wv + (size_t)i0 * CH;

  float aq[4] = {0.f,0.f,0.f,0.f};
  float ak[4] = {0.f,0.f,0.f,0.f};
  float av[4] = {0.f,0.f,0.f,0.f};

  #pragma unroll 16
  for (int c = 0; c < CH; ++c) {
    float xv = xb[(size_t)c * NPOS];
    #pragma unroll
    for (int j = 0; j < 4; ++j) {
      aq[j] += wq[(size_t)j * CH + c] * xv;
      ak[j] += wk[(size_t)j * CH + c] * xv;
      av[j] += wv[(size_t)j * CH + c] * xv;
    }
  }

  // layout: [(b*4 + h)][n][d], d = i&31.  i0%4==0 -> 16B-aligned float4 store.
  const size_t base = (size_t)(b * 4 + (i0 >> 5)) * (NPOS * DH)
                    + (size_t)n * DH + (i0 & 31);
  *(float4*)(Q + base) = make_float4(aq[0], aq[1], aq[2], aq[3]);
  *(float4*)(K + base) = make_float4(ak[0], ak[1], ak[2], ak[3]);
  *(float4*)(V + base) = make_float4(av[0], av[1], av[2], av[3]);
}

// ---------------------------------------------------------------------------
// Kernel B: fused scores -> KAN -> fixed-bound exp -> PV, split over m.
// Thread = query row.  K/V tiles staged in LDS; per-m reads are wave-uniform
// broadcasts (conflict-free).
// ---------------------------------------------------------------------------
__global__ __launch_bounds__(256, 4) void attn_partial(
    const float* __restrict__ Q, const float* __restrict__ K,
    const float* __restrict__ V,
    const float* __restrict__ bwp, const float* __restrict__ swp,
    const float* __restrict__ ssp,
    float* __restrict__ Opart, float* __restrict__ Spart, int mblk)
{
  __shared__ float coefL[8];
  __shared__ float Ks[64][DH];
  __shared__ float Vs[64][DH];

  const int tid = threadIdx.x;
  const int bh  = blockIdx.x;   // 0..7
  const int rt  = blockIdx.y;   // 0..3
  const int sp  = blockIdx.z;   // 0..splits-1

  if (tid < 8) coefL[tid] = swp[tid] * ssp[0];
  __syncthreads();

  const int row = rt * 256 + tid;
  const float* q = Q + ((size_t)bh * NPOS + row) * DH;

  float qr[32];
  #pragma unroll
  for (int j = 0; j < 8; ++j) {
    float4 t = ((const float4*)q)[j];
    qr[4*j+0] = t.x; qr[4*j+1] = t.y; qr[4*j+2] = t.z; qr[4*j+3] = t.w;
  }

  const float base_w = bwp[0];
  float maxc = 0.f;
  #pragma unroll
  for (int k2 = 0; k2 < 8; ++k2) maxc = fmaxf(maxc, fabsf(coefL[k2]));
  const float Bnd = fabsf(base_w) * 6.0f + maxc;   // >= max_x kan(x)

  float O[32];
  #pragma unroll
  for (int j = 0; j < 32; ++j) O[j] = 0.f;
  float Ssum = 0.f;

  const float4* kb = (const float4*)(K + ((size_t)bh * NPOS + (size_t)sp * mblk) * DH);
  const float4* vb = (const float4*)(V + ((size_t)bh * NPOS + (size_t)sp * mblk) * DH);

  for (int t0 = 0; t0 < mblk; t0 += 64) {
    const int TB  = (mblk - t0) < 64 ? (mblk - t0) : 64;
    const int nf4 = TB * DH / 4;                 // float4s per matrix
    __syncthreads();
    for (int idx = tid; idx < nf4; idx += 256) {
      ((float4*)Ks)[idx] = kb[t0 * (DH/4) + idx];
      ((float4*)Vs)[idx] = vb[t0 * (DH/4) + idx];
    }
    __syncthreads();

    #pragma unroll 2
    for (int mm = 0; mm < TB; ++mm) {
      // ---- score: dot(q_row, k_row) (k from LDS, uniform broadcast) ----
      const float4* kr = (const float4*)Ks[mm];
      float s0 = 0.f, s1 = 0.f, s2 = 0.f, s3 = 0.f;
      #pragma unroll
      for (int j = 0; j < 8; ++j) {
        float4 kv = kr[j];
        s0 += qr[4*j+0] * kv.x;
        s1 += qr[4*j+1] * kv.y;
        s2 += qr[4*j+2] * kv.z;
        s3 += qr[4*j+3] * kv.w;
      }
      float s = ((s0 + s1) + (s2 + s3)) * 0.17677669529663687f; // 1/sqrt(32)

      // ---- _safe: clip to [-6,6] ----
      s = fminf(fmaxf(s, -6.0f), 6.0f);

      // ---- KAN: base_w * silu(s) + uniform cubic B-spline ----
      float e   = __expf(-s);
      float sil = s * __builtin_amdgcn_rcpf(1.0f + e);

      float t  = (s + 6.0f) * (1.0f / 2.4f);   // in [0,5]
      float cf = floorf(t);
      cf = fminf(cf, 4.0f);
      int   ci = (int)cf;
      float u  = t - cf;
      float u2 = u * u, u3 = u2 * u;
      float om = 1.0f - u;
      float w0 = om * om * om * (1.0f / 6.0f);
      float w1 = (3.0f * u3 - 6.0f * u2 + 4.0f) * (1.0f / 6.0f);
      float w2 = (-3.0f * u3 + 3.0f * u2 + 3.0f * u + 1.0f) * (1.0f / 6.0f);
      float w3 = u3 * (1.0f / 6.0f);
      float spl = w0 * coefL[ci]     + w1 * coefL[ci + 1] +
                  w2 * coefL[ci + 2] + w3 * coefL[ci + 3];
      float kan = base_w * sil + spl;

      // ---- fixed-bound softmax numerator ----
      float pr = __expf(kan - Bnd);
      Ssum += pr;

      // ---- PV accumulate (v from LDS, uniform broadcast) ----
      const float4* vr = (const float4*)Vs[mm];
      #pragma unroll
      for (int j = 0; j < 8; ++j) {
        float4 vv = vr[j];
        O[4*j+0] += pr * vv.x;
        O[4*j+1] += pr * vv.y;
        O[4*j+2] += pr * vv.z;
        O[4*j+3] += pr * vv.w;
      }
    }
  }

  // partials: Opart [sp][bh][d][n]  (lanes = consecutive n -> coalesced)
  float* ob = Opart + ((size_t)(sp * NBH + bh) * DH) * NPOS;
  #pragma unroll
  for (int d = 0; d < 32; ++d) ob[(size_t)d * NPOS + row] = O[d];
  Spart[(size_t)(sp * NBH + bh) * NPOS + row] = Ssum;
}

// ---------------------------------------------------------------------------
// Kernel C1: denominator reduce:  Sinv[bh][n] = 1 / sum_sp Spart
// ---------------------------------------------------------------------------
__global__ __launch_bounds__(256) void sden_kernel(
    const float* __restrict__ Spart, float* __restrict__ Sinv, int splits)
{
  int gid = blockIdx.x * 256 + threadIdx.x;   // 0..8191
  int n  = gid & (NPOS - 1);
  int bh = gid >> 10;
  float ssum = 0.f;
  #pragma unroll 4
  for (int sp = 0; sp < splits; ++sp)
    ssum += Spart[(size_t)(sp * NBH + bh) * NPOS + n];
  Sinv[gid] = 1.0f / ssum;
}

// ---------------------------------------------------------------------------
// Kernel C2: O reduce + normalize.  Onorm [bh][d][n] == [b][i][n].
// ---------------------------------------------------------------------------
__global__ __launch_bounds__(256) void reduce_kernel(
    const float* __restrict__ Opart, const float* __restrict__ Sinv,
    float* __restrict__ Onorm, int splits)
{
  int gid = blockIdx.x * 256 + threadIdx.x;   // 0..262143
  int n  = gid & (NPOS - 1);
  int d  = (gid >> 10) & 31;
  int bh = gid >> 15;
  float o = 0.f;
  #pragma unroll 4
  for (int sp = 0; sp < splits; ++sp)
    o += Opart[((size_t)(sp * NBH + bh) * DH + d) * NPOS + n];
  Onorm[((size_t)bh * DH + d) * NPOS + n] = o * Sinv[(bh << 10) | n];
}

// ---------------------------------------------------------------------------
// Kernel D: output projection. out[b,c,n] = sum_i Wo[c,i] * Onorm[b*128+i][n]
// 8 accumulators per thread.
// ---------------------------------------------------------------------------
__global__ __launch_bounds__(256) void outproj_kernel(
    const float* __restrict__ Onorm, const float* __restrict__ Wo,
    float* __restrict__ out)
{
  const int lane = threadIdx.x & 63;
  const int it   = threadIdx.x >> 6;
  const int n    = blockIdx.x * 64 + lane;
  const int c0   = blockIdx.y * 32 + it * 8;   // blockIdx.y: 0..7
  const int b    = blockIdx.z;

  const float* ob = Onorm + (size_t)b * INNER * NPOS + n;
  const float* w0 = Wo + (size_t)c0 * INNER;

  float acc[8];
  #pragma unroll
  for (int j = 0; j < 8; ++j) acc[j] = 0.f;

  #pragma unroll 16
  for (int i = 0; i < INNER; ++i) {
    float xv = ob[(size_t)i * NPOS];
    #pragma unroll
    for (int j = 0; j < 8; ++j) acc[j] += w0[(size_t)j * INNER + i] * xv;
  }
  #pragma unroll
  for (int j = 0; j < 8; ++j)
    out[((size_t)(b * CH + c0 + j)) * NPOS + n] = acc[j];
}

// ---------------------------------------------------------------------------
extern "C" void kernel_launch(void* const* d_in, const int* in_sizes, int n_in,
                              void* d_out, int out_size, void* d_ws, size_t ws_size,
                              hipStream_t stream)
{
  const float* x  = (const float*)d_in[0];
  const float* Wq = (const float*)d_in[1];
  const float* Wk = (const float*)d_in[2];
  const float* Wv = (const float*)d_in[3];
  const float* Wo = (const float*)d_in[4];
  const float* bw = (const float*)d_in[5];
  const float* sw = (const float*)d_in[6];
  const float* ss = (const float*)d_in[7];
  float* out = (float*)d_out;
  float* ws  = (float*)d_ws;

  // pick splits that fit the workspace
  int splits = 32;
  while (splits > 1) {
    size_t need = ((size_t)3 * NBH * NPOS * DH          // Q,K,V
                 + (size_t)splits * NBH * DH * NPOS     // Opart
                 + (size_t)splits * NBH * NPOS          // Spart
                 + (size_t)NBH * NPOS                   // Sinv
                 + (size_t)NBH * DH * NPOS)             // Onorm
                 * sizeof(float);
    if (need <= ws_size) break;
    splits >>= 1;
  }

  float* Q     = ws;
  float* K     = Q + (size_t)NBH * NPOS * DH;
  float* V     = K + (size_t)NBH * NPOS * DH;
  float* Opart = V + (size_t)NBH * NPOS * DH;
  float* Spart = Opart + (size_t)splits * NBH * DH * NPOS;
  float* Sinv  = Spart + (size_t)splits * NBH * NPOS;
  float* Onorm = Sinv + (size_t)NBH * NPOS;

  proj_kernel<<<dim3(16, 8, 2), 256, 0, stream>>>(x, Wq, Wk, Wv, Q, K, V);
  attn_partial<<<dim3(8, 4, splits), 256, 0, stream>>>(
      Q, K, V, bw, sw, ss, Opart, Spart, NPOS / splits);
  sden_kernel<<<dim3(NBH * NPOS / 256), 256, 0, stream>>>(Spart, Sinv, splits);
  reduce_kernel<<<dim3((NBH * DH * NPOS) / 256), 256, 0, stream>>>(
      Opart, Sinv, Onorm, splits);
  outproj_kernel<<<dim3(16, 8, 2), 256, 0, stream>>>(Onorm, Wo, out);
}

// Round 3
// 101.325 us; speedup vs baseline: 1.0755x; 1.0755x over previous
//
#include <hip/hip_runtime.h>
#include <math.h>

#define NPOS 1024   // H*W
#define DH   32     // dim head
#define NBH  8      // B * HEADS
#define CH   256
#define INNER 128   // HEADS*DIM_HEAD
#define SPLITS 32   // m-splits (tile of 32 key rows per WG)

// ---------------------------------------------------------------------------
// Kernel A: fused QKV projection.  out_p[b,i,n] = sum_c W_p[i,c] * x[b,c,n]
// 6 accumulators (2 i x {Q,K,V}); Q pre-scaled by 1/sqrt(dh). Grid 512 WGs.
// ---------------------------------------------------------------------------
__global__ __launch_bounds__(256) void proj_kernel(
    const float* __restrict__ x, const float* __restrict__ Wq,
    const float* __restrict__ Wk, const float* __restrict__ Wv,
    float* __restrict__ Q, float* __restrict__ K, float* __restrict__ V)
{
  const int lane = threadIdx.x & 63;
  const int it   = threadIdx.x >> 6;        // 0..3
  const int n    = blockIdx.x * 64 + lane;  // 0..1023
  const int i0   = blockIdx.y * 8 + it * 2; // even, 0..126
  const int b    = blockIdx.z;

  const float* xb = x  + (size_t)b * CH * NPOS + n;
  const float* wq = Wq + (size_t)i0 * CH;
  const float* wk = Wk + (size_t)i0 * CH;
  const float* wv = Wv + (size_t)i0 * CH;

  float aq0 = 0.f, aq1 = 0.f, ak0 = 0.f, ak1 = 0.f, av0 = 0.f, av1 = 0.f;

  #pragma unroll 16
  for (int c = 0; c < CH; ++c) {
    float xv = xb[(size_t)c * NPOS];
    aq0 += wq[c]      * xv;
    aq1 += wq[CH + c] * xv;
    ak0 += wk[c]      * xv;
    ak1 += wk[CH + c] * xv;
    av0 += wv[c]      * xv;
    av1 += wv[CH + c] * xv;
  }

  const float qs = 0.17677669529663687f;  // 1/sqrt(32), folded into Q
  const size_t base = (size_t)(b * 4 + (i0 >> 5)) * (NPOS * DH)
                    + (size_t)n * DH + (i0 & 31);
  *(float2*)(Q + base) = make_float2(aq0 * qs, aq1 * qs);
  *(float2*)(K + base) = make_float2(ak0, ak1);
  *(float2*)(V + base) = make_float2(av0, av1);
}

// ---------------------------------------------------------------------------
// Kernel B: fused scores -> KAN -> fixed-bound exp -> PV.
// K/V tile (32 rows each) lives in lane-owned registers: lanes 0-31 hold K
// rows, lanes 32-63 hold V rows; per-m broadcast via v_readlane (VALU pipe,
// not LDS). Each thread processes 2 query rows. Partials accumulated into
// global Oacc/Sden via atomicAdd (no Opart round-trip).
// ---------------------------------------------------------------------------
__global__ __launch_bounds__(256, 2) void attn_partial(
    const float* __restrict__ Q, const float* __restrict__ K,
    const float* __restrict__ V,
    const float* __restrict__ bwp, const float* __restrict__ swp,
    const float* __restrict__ ssp,
    float* __restrict__ Oacc, float* __restrict__ Sden)
{
  __shared__ float tab[20];   // per-cell cubic poly: tab[p*5 + cell]

  const int tid = threadIdx.x;
  const int bh  = blockIdx.x;   // 0..7
  const int rt  = blockIdx.y;   // 0..1
  const int sp  = blockIdx.z;   // 0..31

  // Build per-cell polynomial table from spline coefs (20 threads).
  if (tid < 20) {
    const int cell = tid % 5, p = tid / 5;
    const float sc = ssp[0];
    const float C0 = swp[cell] * sc,     C1 = swp[cell + 1] * sc;
    const float C2 = swp[cell + 2] * sc, C3 = swp[cell + 3] * sc;
    float a;
    if      (p == 0) a = (C0 + 4.f * C1 + C2) * (1.f / 6.f);
    else if (p == 1) a = (-3.f * C0 + 3.f * C2) * (1.f / 6.f);
    else if (p == 2) a = (3.f * C0 - 6.f * C1 + 3.f * C2) * (1.f / 6.f);
    else             a = (-C0 + 3.f * C1 - 3.f * C2 + C3) * (1.f / 6.f);
    tab[p * 5 + cell] = a;
  }
  __syncthreads();

  const float base_w = bwp[0];
  const float sc = ssp[0];
  float maxc = 0.f;
  #pragma unroll
  for (int k2 = 0; k2 < 8; ++k2) maxc = fmaxf(maxc, fabsf(swp[k2] * sc));
  const float Bnd = fabsf(base_w) * 6.0f + maxc;   // >= max_x kan(x), uniform

  // rows: r0 = rt*512 + tid, r1 = r0 + 256 (lane-consecutive -> coalesced)
  const int r0 = rt * 512 + tid;
  const int r1 = r0 + 256;

  float qa[32], qb[32];
  {
    const float4* q0 = (const float4*)(Q + ((size_t)bh * NPOS + r0) * DH);
    const float4* q1 = (const float4*)(Q + ((size_t)bh * NPOS + r1) * DH);
    #pragma unroll
    for (int j = 0; j < 8; ++j) {
      float4 t0 = q0[j], t1 = q1[j];
      qa[4*j+0] = t0.x; qa[4*j+1] = t0.y; qa[4*j+2] = t0.z; qa[4*j+3] = t0.w;
      qb[4*j+0] = t1.x; qb[4*j+1] = t1.y; qb[4*j+2] = t1.z; qb[4*j+3] = t1.w;
    }
  }

  // lane-owned K/V tile: lanes 0-31 = K rows, lanes 32-63 = V rows
  const int lane = tid & 63;
  float reg[32];
  {
    const int krow = sp * 32 + (lane & 31);
    const float* src = ((lane < 32) ? K : V) + ((size_t)bh * NPOS + krow) * DH;
    const float4* s4 = (const float4*)src;
    #pragma unroll
    for (int j = 0; j < 8; ++j) {
      float4 t = s4[j];
      reg[4*j+0] = t.x; reg[4*j+1] = t.y; reg[4*j+2] = t.z; reg[4*j+3] = t.w;
    }
  }

  float oa[32], ob[32];
  #pragma unroll
  for (int j = 0; j < 32; ++j) { oa[j] = 0.f; ob[j] = 0.f; }
  float ssA = 0.f, ssB = 0.f;

  #pragma unroll 2
  for (int mm = 0; mm < 32; ++mm) {
    // ---- broadcast K row mm from lane mm; dual dot (Q pre-scaled) ----
    float sA0 = 0.f, sA1 = 0.f, sA2 = 0.f, sA3 = 0.f;
    float sB0 = 0.f, sB1 = 0.f, sB2 = 0.f, sB3 = 0.f;
    #pragma unroll
    for (int j = 0; j < 32; j += 4) {
      float k0 = __int_as_float(__builtin_amdgcn_readlane(__float_as_int(reg[j+0]), mm));
      float k1 = __int_as_float(__builtin_amdgcn_readlane(__float_as_int(reg[j+1]), mm));
      float k2 = __int_as_float(__builtin_amdgcn_readlane(__float_as_int(reg[j+2]), mm));
      float k3 = __int_as_float(__builtin_amdgcn_readlane(__float_as_int(reg[j+3]), mm));
      sA0 = fmaf(k0, qa[j+0], sA0);  sB0 = fmaf(k0, qb[j+0], sB0);
      sA1 = fmaf(k1, qa[j+1], sA1);  sB1 = fmaf(k1, qb[j+1], sB1);
      sA2 = fmaf(k2, qa[j+2], sA2);  sB2 = fmaf(k2, qb[j+2], sB2);
      sA3 = fmaf(k3, qa[j+3], sA3);  sB3 = fmaf(k3, qb[j+3], sB3);
    }
    float sA = (sA0 + sA1) + (sA2 + sA3);
    float sB = (sB0 + sB1) + (sB2 + sB3);

    float prA, prB;
    #pragma unroll
    for (int r = 0; r < 2; ++r) {
      float s = (r == 0) ? sA : sB;
      s = fminf(fmaxf(s, -6.0f), 6.0f);
      // silu
      float e   = __expf(-s);
      float sil = s * __builtin_amdgcn_rcpf(1.0f + e);
      // spline via per-cell cubic (Horner)
      float t  = fmaf(s, (1.0f / 2.4f), 2.5f);   // (s+6)/2.4 in [0,5]
      float cf = fminf(floorf(t), 4.0f);
      int   ci = (int)cf;
      float u  = t - cf;
      float a0 = tab[ci], a1 = tab[5 + ci], a2 = tab[10 + ci], a3 = tab[15 + ci];
      float spl = fmaf(fmaf(fmaf(a3, u, a2), u, a1), u, a0);
      float kan = fmaf(base_w, sil, spl);
      float pr  = __expf(kan - Bnd);
      if (r == 0) prA = pr; else prB = pr;
    }
    ssA += prA;
    ssB += prB;

    // ---- broadcast V row mm from lane 32+mm; PV accumulate ----
    #pragma unroll
    for (int j = 0; j < 32; ++j) {
      float vv = __int_as_float(__builtin_amdgcn_readlane(__float_as_int(reg[j]), 32 + mm));
      oa[j] = fmaf(prA, vv, oa[j]);
      ob[j] = fmaf(prB, vv, ob[j]);
    }
  }

  // ---- accumulate partials: Oacc [bh][d][n], Sden [bh][n] ----
  float* obase = Oacc + (size_t)bh * DH * NPOS;
  #pragma unroll
  for (int d = 0; d < 32; ++d) {
    atomicAdd(obase + (size_t)d * NPOS + r0, oa[d]);
    atomicAdd(obase + (size_t)d * NPOS + r1, ob[d]);
  }
  atomicAdd(Sden + (size_t)bh * NPOS + r0, ssA);
  atomicAdd(Sden + (size_t)bh * NPOS + r1, ssB);
}

// ---------------------------------------------------------------------------
// Kernel C: output projection with fused normalization.
// out[b,c,n] = sum_i Wo[c,i] * Oacc[b*128+i][n] / Sden[b*4 + i/32][n]
// ---------------------------------------------------------------------------
__global__ __launch_bounds__(256) void outproj_kernel(
    const float* __restrict__ Oacc, const float* __restrict__ Sden,
    const float* __restrict__ Wo, float* __restrict__ out)
{
  const int lane = threadIdx.x & 63;
  const int it   = threadIdx.x >> 6;
  const int n    = blockIdx.x * 64 + lane;
  const int c0   = blockIdx.y * 16 + it * 4;   // blockIdx.y: 0..15
  const int b    = blockIdx.z;

  const float* ob = Oacc + (size_t)b * INNER * NPOS + n;
  const float* sd = Sden + (size_t)b * 4 * NPOS + n;
  const float* w0 = Wo + (size_t)c0 * INNER;

  float acc[4] = {0.f, 0.f, 0.f, 0.f};

  #pragma unroll
  for (int h = 0; h < 4; ++h) {
    const float si = __builtin_amdgcn_rcpf(sd[(size_t)h * NPOS]);
    #pragma unroll 8
    for (int i2 = 0; i2 < 32; ++i2) {
      const int i = h * 32 + i2;
      float xs = ob[(size_t)i * NPOS] * si;
      acc[0] += w0[i]             * xs;
      acc[1] += w0[INNER + i]     * xs;
      acc[2] += w0[2 * INNER + i] * xs;
      acc[3] += w0[3 * INNER + i] * xs;
    }
  }
  #pragma unroll
  for (int j = 0; j < 4; ++j)
    out[((size_t)(b * CH + c0 + j)) * NPOS + n] = acc[j];
}

// ---------------------------------------------------------------------------
extern "C" void kernel_launch(void* const* d_in, const int* in_sizes, int n_in,
                              void* d_out, int out_size, void* d_ws, size_t ws_size,
                              hipStream_t stream)
{
  const float* x  = (const float*)d_in[0];
  const float* Wq = (const float*)d_in[1];
  const float* Wk = (const float*)d_in[2];
  const float* Wv = (const float*)d_in[3];
  const float* Wo = (const float*)d_in[4];
  const float* bw = (const float*)d_in[5];
  const float* sw = (const float*)d_in[6];
  const float* ss = (const float*)d_in[7];
  float* out = (float*)d_out;
  float* ws  = (float*)d_ws;

  // workspace layout (floats): Oacc[8*32*1024] | Sden[8*1024] | Q | K | V
  float* Oacc = ws;
  float* Sden = Oacc + (size_t)NBH * DH * NPOS;
  float* Q    = Sden + (size_t)NBH * NPOS;
  float* K    = Q + (size_t)NBH * NPOS * DH;
  float* V    = K + (size_t)NBH * NPOS * DH;

  // zero the atomic accumulators (Oacc + Sden are contiguous)
  hipMemsetAsync(Oacc, 0, ((size_t)NBH * DH * NPOS + (size_t)NBH * NPOS) * sizeof(float), stream);

  proj_kernel<<<dim3(16, 16, 2), 256, 0, stream>>>(x, Wq, Wk, Wv, Q, K, V);
  attn_partial<<<dim3(8, 2, SPLITS), 256, 0, stream>>>(
      Q, K, V, bw, sw, ss, Oacc, Sden);
  outproj_kernel<<<dim3(16, 16, 2), 256, 0, stream>>>(Oacc, Sden, Wo, out);
}